// Round 1
// baseline (564.597 us; speedup 1.0000x reference)
//
#include <hip/hip_runtime.h>
#include <math.h>

// Problem constants (match reference)
#define NUM_CLASSES 80
#define ALPHA 0.25f
#define GAMMA 2.0f
#define BETA 0.11f
#define POS_THR 0.5f
#define NEG_THR 0.4f
#define B_CNT 8
#define A_CNT 98304
#define G_CNT 32

// ws layout:
//   [0]  float cls_sum
//   [4]  float reg_sum
//   [8]  float num_pos
//   [16] signed char cls_t[B*A]   (-1 ignore, 0 bg, 1..80 fg label)

__device__ __forceinline__ float block_reduce_sum(float v, float* s) {
    #pragma unroll
    for (int off = 32; off > 0; off >>= 1) v += __shfl_down(v, off, 64);
    const int wave = threadIdx.x >> 6;
    if ((threadIdx.x & 63) == 0) s[wave] = v;
    __syncthreads();
    return (threadIdx.x == 0) ? (s[0] + s[1] + s[2] + s[3]) : 0.0f;
}

__global__ __launch_bounds__(256) void match_kernel(
    const float* __restrict__ reg_pred,   // [B,A,4]
    const float* __restrict__ anchors,    // [A,4]
    const float* __restrict__ gt_boxes,   // [B,G,4]
    const int*   __restrict__ gt_labels,  // [B,G]
    signed char* __restrict__ cls_t_out,  // [B*A]
    float* __restrict__ accum)
{
    __shared__ float4 s_gt[G_CNT];
    __shared__ int    s_lab[G_CNT];
    __shared__ float  s_red[4];
    __shared__ float  s_cnt[4];

    const int blocks_per_batch = A_CNT / 256;           // 384, exact
    const int b = blockIdx.x / blocks_per_batch;
    const int a = (blockIdx.x % blocks_per_batch) * 256 + threadIdx.x;

    if (threadIdx.x < G_CNT) {
        s_gt[threadIdx.x]  = ((const float4*)gt_boxes)[b * G_CNT + threadIdx.x];
        s_lab[threadIdx.x] = gt_labels[b * G_CNT + threadIdx.x];
    }
    __syncthreads();

    const float4 an = ((const float4*)anchors)[a];
    const float aw = an.z - an.x;
    const float ah = an.w - an.y;
    const float area_a = aw * ah;

    float best = -1.0f;
    int bidx = 0;
    #pragma unroll
    for (int g = 0; g < G_CNT; ++g) {
        const float4 gb = s_gt[g];
        const float ltx = fmaxf(an.x, gb.x);
        const float lty = fmaxf(an.y, gb.y);
        const float rbx = fminf(an.z, gb.z);
        const float rby = fminf(an.w, gb.w);
        const float w = fmaxf(rbx - ltx, 0.0f);
        const float h = fmaxf(rby - lty, 0.0f);
        const float inter = w * h;
        const float area_g = (gb.z - gb.x) * (gb.w - gb.y);
        const float iou = inter / (area_a + area_g - inter);
        if (iou > best) { best = iou; bidx = g; }   // first-max == jnp argmax
    }

    const bool pos = (best >= POS_THR);
    const int lab = s_lab[bidx];
    signed char ct = pos ? (signed char)lab : ((best < NEG_THR) ? (signed char)0 : (signed char)-1);
    cls_t_out[b * A_CNT + a] = ct;

    float regsum = 0.0f;
    if (pos) {
        const float4 gb = s_gt[bidx];
        const float gw = gb.z - gb.x;
        const float gh = gb.w - gb.y;
        const float gx = gb.x + 0.5f * gw;
        const float gy = gb.y + 0.5f * gh;
        const float ax = an.x + 0.5f * aw;
        const float ay = an.y + 0.5f * ah;
        const float t0 = (gx - ax) / aw;
        const float t1 = (gy - ay) / ah;
        const float t2 = logf(gw / aw);
        const float t3 = logf(gh / ah);
        const float4 rp = ((const float4*)reg_pred)[b * A_CNT + a];
        const float d0 = fabsf(rp.x - t0);
        const float d1 = fabsf(rp.y - t1);
        const float d2 = fabsf(rp.z - t2);
        const float d3 = fabsf(rp.w - t3);
        const float s0 = (d0 < BETA) ? 0.5f * d0 * d0 / BETA : d0 - 0.5f * BETA;
        const float s1 = (d1 < BETA) ? 0.5f * d1 * d1 / BETA : d1 - 0.5f * BETA;
        const float s2 = (d2 < BETA) ? 0.5f * d2 * d2 / BETA : d2 - 0.5f * BETA;
        const float s3 = (d3 < BETA) ? 0.5f * d3 * d3 / BETA : d3 - 0.5f * BETA;
        regsum = s0 + s1 + s2 + s3;
    }

    // block reduce reg sum
    float rs = block_reduce_sum(regsum, s_red);
    __syncthreads();
    float cnt = block_reduce_sum(pos ? 1.0f : 0.0f, s_cnt);
    if (threadIdx.x == 0) {
        if (rs != 0.0f) atomicAdd(&accum[1], rs);
        if (cnt != 0.0f) atomicAdd(&accum[2], cnt);
    }
}

__device__ __forceinline__ float focal_term(float x, bool is_t) {
    const float t = is_t ? 1.0f : 0.0f;
    const float e = expf(-fabsf(x));
    const float bce = fmaxf(x, 0.0f) - x * t + log1pf(e);
    const float r = 1.0f / (1.0f + e);
    const float prob = (x >= 0.0f) ? r : e * r;           // sigmoid(x)
    const float p_t = prob * t + (1.0f - prob) * (1.0f - t);
    const float af = ALPHA * t + (1.0f - ALPHA) * (1.0f - t);
    const float om = 1.0f - p_t;
    return af * om * om * bce;
}

__global__ __launch_bounds__(256) void focal_kernel(
    const float* __restrict__ cls_pred,        // [B*A*80]
    const signed char* __restrict__ cls_t,     // [B*A]
    float* __restrict__ accum)
{
    __shared__ float s_red[4];
    const int total4 = B_CNT * A_CNT * (NUM_CLASSES / 4);  // 15,728,640
    const int stride = gridDim.x * blockDim.x;
    float sum = 0.0f;
    for (int i = blockIdx.x * blockDim.x + threadIdx.x; i < total4; i += stride) {
        const int anchor = i / (NUM_CLASSES / 4);
        const int chunk = i - anchor * (NUM_CLASSES / 4);
        const signed char ct = cls_t[anchor];
        if (ct >= 0) {
            const float4 x4 = ((const float4*)cls_pred)[i];
            const int tgt = (int)ct - 1;      // -1 for background -> no match
            const int c0 = chunk * 4;
            sum += focal_term(x4.x, c0 + 0 == tgt);
            sum += focal_term(x4.y, c0 + 1 == tgt);
            sum += focal_term(x4.z, c0 + 2 == tgt);
            sum += focal_term(x4.w, c0 + 3 == tgt);
        }
    }
    const float bs = block_reduce_sum(sum, s_red);
    if (threadIdx.x == 0 && bs != 0.0f) atomicAdd(&accum[0], bs);
}

__global__ void finalize_kernel(const float* __restrict__ accum, float* __restrict__ out) {
    const float cs = accum[0];
    const float rs = accum[1];
    const float np = accum[2];
    const float denom = fmaxf(np, 1.0f);
    const float cl = (np > 0.0f) ? cs / denom : cs;
    const float rl = (np > 0.0f) ? rs / denom : 0.0f;
    out[0] = cl + rl;
    out[1] = cl;
    out[2] = rl;
}

extern "C" void kernel_launch(void* const* d_in, const int* in_sizes, int n_in,
                              void* d_out, int out_size, void* d_ws, size_t ws_size,
                              hipStream_t stream) {
    const float* cls_pred = (const float*)d_in[0];   // [B,A,80]
    const float* reg_pred = (const float*)d_in[1];   // [B,A,4]
    const float* anchors  = (const float*)d_in[2];   // [A,4]
    const float* gt_boxes = (const float*)d_in[3];   // [B,G,4]
    const int*   gt_labels= (const int*)d_in[4];     // [B,G]
    float* out = (float*)d_out;

    float* accum = (float*)d_ws;                     // 3 floats
    signed char* cls_t = (signed char*)d_ws + 16;    // B*A bytes

    hipMemsetAsync(d_ws, 0, 16, stream);

    const int blocks1 = (B_CNT * A_CNT) / 256;       // 3072
    match_kernel<<<blocks1, 256, 0, stream>>>(reg_pred, anchors, gt_boxes, gt_labels, cls_t, accum);

    focal_kernel<<<4096, 256, 0, stream>>>(cls_pred, cls_t, accum);

    finalize_kernel<<<1, 1, 0, stream>>>(accum, out);
}

// Round 2
// 450.282 us; speedup vs baseline: 1.2539x; 1.2539x over previous
//
#include <hip/hip_runtime.h>
#include <math.h>

// Problem constants (match reference)
#define NUM_CLASSES 80
#define ALPHA 0.25f
#define GAMMA 2.0f
#define BETA 0.11f
#define POS_THR 0.5f
#define NEG_THR 0.4f
#define B_CNT 8
#define A_CNT 98304
#define G_CNT 32

// ws layout:
//   [0]  float cls_sum
//   [4]  float reg_sum
//   [8]  float num_pos
//   [16] signed char cls_t[B*A]   (-1 ignore, 0 bg, 1..80 fg label)

__device__ __forceinline__ float block_reduce_sum(float v, float* s) {
    #pragma unroll
    for (int off = 32; off > 0; off >>= 1) v += __shfl_down(v, off, 64);
    const int wave = threadIdx.x >> 6;
    if ((threadIdx.x & 63) == 0) s[wave] = v;
    __syncthreads();
    return (threadIdx.x == 0) ? (s[0] + s[1] + s[2] + s[3]) : 0.0f;
}

__global__ __launch_bounds__(256) void match_kernel(
    const float* __restrict__ reg_pred,   // [B,A,4]
    const float* __restrict__ anchors,    // [A,4]
    const float* __restrict__ gt_boxes,   // [B,G,4]
    const int*   __restrict__ gt_labels,  // [B,G]
    signed char* __restrict__ cls_t_out,  // [B*A]
    float* __restrict__ accum)
{
    __shared__ float4 s_gt[G_CNT];
    __shared__ int    s_lab[G_CNT];
    __shared__ float  s_red[4];
    __shared__ float  s_cnt[4];

    const int blocks_per_batch = A_CNT / 256;           // 384, exact
    const int b = blockIdx.x / blocks_per_batch;
    const int a = (blockIdx.x % blocks_per_batch) * 256 + threadIdx.x;

    if (threadIdx.x < G_CNT) {
        s_gt[threadIdx.x]  = ((const float4*)gt_boxes)[b * G_CNT + threadIdx.x];
        s_lab[threadIdx.x] = gt_labels[b * G_CNT + threadIdx.x];
    }
    __syncthreads();

    const float4 an = ((const float4*)anchors)[a];
    const float aw = an.z - an.x;
    const float ah = an.w - an.y;
    const float area_a = aw * ah;

    float best = -1.0f;
    int bidx = 0;
    #pragma unroll
    for (int g = 0; g < G_CNT; ++g) {
        const float4 gb = s_gt[g];
        const float ltx = fmaxf(an.x, gb.x);
        const float lty = fmaxf(an.y, gb.y);
        const float rbx = fminf(an.z, gb.z);
        const float rby = fminf(an.w, gb.w);
        const float w = fmaxf(rbx - ltx, 0.0f);
        const float h = fmaxf(rby - lty, 0.0f);
        const float inter = w * h;
        const float area_g = (gb.z - gb.x) * (gb.w - gb.y);
        const float iou = inter / (area_a + area_g - inter);
        if (iou > best) { best = iou; bidx = g; }   // first-max == jnp argmax
    }

    const bool pos = (best >= POS_THR);
    const int lab = s_lab[bidx];
    signed char ct = pos ? (signed char)lab : ((best < NEG_THR) ? (signed char)0 : (signed char)-1);
    cls_t_out[b * A_CNT + a] = ct;

    float regsum = 0.0f;
    if (pos) {
        const float4 gb = s_gt[bidx];
        const float gw = gb.z - gb.x;
        const float gh = gb.w - gb.y;
        const float gx = gb.x + 0.5f * gw;
        const float gy = gb.y + 0.5f * gh;
        const float ax = an.x + 0.5f * aw;
        const float ay = an.y + 0.5f * ah;
        const float t0 = (gx - ax) / aw;
        const float t1 = (gy - ay) / ah;
        const float t2 = __logf(gw / aw);
        const float t3 = __logf(gh / ah);
        const float4 rp = ((const float4*)reg_pred)[b * A_CNT + a];
        const float d0 = fabsf(rp.x - t0);
        const float d1 = fabsf(rp.y - t1);
        const float d2 = fabsf(rp.z - t2);
        const float d3 = fabsf(rp.w - t3);
        const float s0 = (d0 < BETA) ? 0.5f * d0 * d0 / BETA : d0 - 0.5f * BETA;
        const float s1 = (d1 < BETA) ? 0.5f * d1 * d1 / BETA : d1 - 0.5f * BETA;
        const float s2 = (d2 < BETA) ? 0.5f * d2 * d2 / BETA : d2 - 0.5f * BETA;
        const float s3 = (d3 < BETA) ? 0.5f * d3 * d3 / BETA : d3 - 0.5f * BETA;
        regsum = s0 + s1 + s2 + s3;
    }

    // block reduce reg sum
    float rs = block_reduce_sum(regsum, s_red);
    __syncthreads();
    float cnt = block_reduce_sum(pos ? 1.0f : 0.0f, s_cnt);
    if (threadIdx.x == 0) {
        if (rs != 0.0f) atomicAdd(&accum[1], rs);
        if (cnt != 0.0f) atomicAdd(&accum[2], cnt);
    }
}

// Fast focal term using HW transcendentals (v_exp_f32 / v_log_f32 / v_rcp_f32).
// Derivation (matches reference exactly in exact arithmetic):
//   e = exp(-|x|), l = log(1+e), prob = sigmoid(x)
//   t=0: focal = 0.75 * prob^2        * (max( x,0) + l)   [= prob^2 * softplus(x)  * (1-ALPHA)]
//   t=1: focal = 0.25 * (1-prob)^2    * (max(-x,0) + l)   [= (1-prob)^2 * softplus(-x) * ALPHA]
__device__ __forceinline__ float focal_fast(float x, bool is_t) {
    const float ax = fabsf(x);
    const float e  = __expf(-ax);                       // v_exp_f32 path
    const float op = 1.0f + e;
    const float l  = __logf(op);                        // v_log_f32 path
    const float r  = __builtin_amdgcn_rcpf(op);         // v_rcp_f32
    const float prob = (x >= 0.0f) ? r : e * r;         // sigmoid(x)
    const float p  = is_t ? (1.0f - prob) : prob;       // (1 - p_t)
    const float mx = is_t ? fmaxf(-x, 0.0f) : fmaxf(x, 0.0f);
    const float af = is_t ? ALPHA : (1.0f - ALPHA);
    return af * p * p * (mx + l);
}

__global__ __launch_bounds__(256) void focal_kernel(
    const float* __restrict__ cls_pred,        // [B*A*80]
    const signed char* __restrict__ cls_t,     // [B*A]
    float* __restrict__ accum)
{
    __shared__ float s_red[4];
    const int total4 = B_CNT * A_CNT * (NUM_CLASSES / 4);  // 15,728,640
    const int stride = gridDim.x * blockDim.x;
    float sum = 0.0f;
    for (int i = blockIdx.x * blockDim.x + threadIdx.x; i < total4; i += stride) {
        const int anchor = i / (NUM_CLASSES / 4);
        const int chunk = i - anchor * (NUM_CLASSES / 4);
        const signed char ct = cls_t[anchor];
        if (ct >= 0) {
            const float4 x4 = ((const float4*)cls_pred)[i];
            const int tgt = (int)ct - 1;      // -1 for background -> no match
            const int c0 = chunk * 4;
            sum += focal_fast(x4.x, c0 + 0 == tgt);
            sum += focal_fast(x4.y, c0 + 1 == tgt);
            sum += focal_fast(x4.z, c0 + 2 == tgt);
            sum += focal_fast(x4.w, c0 + 3 == tgt);
        }
    }
    const float bs = block_reduce_sum(sum, s_red);
    if (threadIdx.x == 0 && bs != 0.0f) atomicAdd(&accum[0], bs);
}

__global__ void finalize_kernel(const float* __restrict__ accum, float* __restrict__ out) {
    const float cs = accum[0];
    const float rs = accum[1];
    const float np = accum[2];
    const float denom = fmaxf(np, 1.0f);
    const float cl = (np > 0.0f) ? cs / denom : cs;
    const float rl = (np > 0.0f) ? rs / denom : 0.0f;
    out[0] = cl + rl;
    out[1] = cl;
    out[2] = rl;
}

extern "C" void kernel_launch(void* const* d_in, const int* in_sizes, int n_in,
                              void* d_out, int out_size, void* d_ws, size_t ws_size,
                              hipStream_t stream) {
    const float* cls_pred = (const float*)d_in[0];   // [B,A,80]
    const float* reg_pred = (const float*)d_in[1];   // [B,A,4]
    const float* anchors  = (const float*)d_in[2];   // [A,4]
    const float* gt_boxes = (const float*)d_in[3];   // [B,G,4]
    const int*   gt_labels= (const int*)d_in[4];     // [B,G]
    float* out = (float*)d_out;

    float* accum = (float*)d_ws;                     // 3 floats
    signed char* cls_t = (signed char*)d_ws + 16;    // B*A bytes

    hipMemsetAsync(d_ws, 0, 16, stream);

    const int blocks1 = (B_CNT * A_CNT) / 256;       // 3072
    match_kernel<<<blocks1, 256, 0, stream>>>(reg_pred, anchors, gt_boxes, gt_labels, cls_t, accum);

    focal_kernel<<<4096, 256, 0, stream>>>(cls_pred, cls_t, accum);

    finalize_kernel<<<1, 1, 0, stream>>>(accum, out);
}